// Round 1
// baseline (980.440 us; speedup 1.0000x reference)
//
#include <hip/hip_runtime.h>

// GraphSAGE forward: 3×(SAGEConv + shared Wm/ReLU) -> concat -> global mean pool -> MLP
// Sizes fixed by the reference.
#define N_NODES 50000
#define N_EDGES 800000
#define D 64
#define N_GRAPHS 512
#define D_TARGET 10

// ---- degree per node (float) and node-count per graph, computed once ----
__global__ void count_kernel(const int* __restrict__ dst, const int* __restrict__ batch,
                             float* __restrict__ deg, float* __restrict__ gcnt) {
    int i = blockIdx.x * blockDim.x + threadIdx.x;
    if (i < N_EDGES) atomicAdd(&deg[dst[i]], 1.0f);
    if (i < N_NODES) atomicAdd(&gcnt[batch[i]], 1.0f);
}

// ---- scatter-add of h[src] into agg[dst]; one wave (64 lanes) per edge ----
__global__ void scatter_kernel(const float* __restrict__ h, const int* __restrict__ src,
                               const int* __restrict__ dst, float* __restrict__ agg) {
    int gid  = blockIdx.x * blockDim.x + threadIdx.x;
    int e    = gid >> 6;
    int lane = gid & 63;
    if (e < N_EDGES) {
        int s = src[e];
        int d = dst[e];
        atomicAdd(&agg[d * D + lane], h[s * D + lane]);
    }
}

// ---- fused node update:
//   mean = agg/max(deg,1)
//   t    = mean@Wl + bl + h@Wr
//   h'   = relu(t@Wm + bm)
//   h_out[n] = h'; gsum[batch[n]][col_off + j] += h'[j]
// NPB nodes per block, 64 threads per node. Weights staged in LDS.
template <int NPB>
__global__ void node_kernel(const float* __restrict__ h_in, const float* __restrict__ agg,
                            const float* __restrict__ deg,
                            const float* __restrict__ Wl, const float* __restrict__ bl,
                            const float* __restrict__ Wr,
                            const float* __restrict__ Wm, const float* __restrict__ bm,
                            const int* __restrict__ batch,
                            float* __restrict__ h_out, float* __restrict__ gsum, int col_off) {
    __shared__ float sWl[D * D];
    __shared__ float sWr[D * D];
    __shared__ float sWm[D * D];
    __shared__ float sx[NPB][D];   // root features
    __shared__ float sm[NPB][D];   // mean-aggregated neighbor features
    __shared__ float st[NPB][D];   // intermediate t

    int t = threadIdx.x;
    for (int i = t; i < D * D; i += blockDim.x) {
        sWl[i] = Wl[i];
        sWr[i] = Wr[i];
        sWm[i] = Wm[i];
    }
    int sub  = t >> 6;
    int lane = t & 63;
    int node = blockIdx.x * NPB + sub;

    float xv = 0.f, mv = 0.f;
    if (node < N_NODES) {
        xv = h_in[node * D + lane];
        float dg = deg[node];
        if (dg < 1.f) dg = 1.f;
        mv = agg[node * D + lane] / dg;
    }
    sx[sub][lane] = xv;
    sm[sub][lane] = mv;
    __syncthreads();

    float acc = bl[lane];
#pragma unroll 8
    for (int k = 0; k < D; ++k)
        acc += sm[sub][k] * sWl[k * D + lane] + sx[sub][k] * sWr[k * D + lane];
    st[sub][lane] = acc;
    __syncthreads();

    float acc2 = bm[lane];
#pragma unroll 8
    for (int k = 0; k < D; ++k)
        acc2 += st[sub][k] * sWm[k * D + lane];
    float hv = acc2 > 0.f ? acc2 : 0.f;

    if (node < N_NODES) {
        h_out[node * D + lane] = hv;
        atomicAdd(&gsum[batch[node] * (3 * D) + col_off + lane], hv);
    }
}

// ---- pooled MLP: g = gsum/cnt; t = relu(g@W1+b1); out = t@W2+b2 ----
__global__ void pool_mlp_kernel(const float* __restrict__ gsum, const float* __restrict__ gcnt,
                                const float* __restrict__ W1, const float* __restrict__ b1,
                                const float* __restrict__ W2, const float* __restrict__ b2,
                                float* __restrict__ out) {
    __shared__ float g[3 * D];
    __shared__ float tt[D];
    int gr = blockIdx.x;
    int t  = threadIdx.x;  // 64 threads
    float cnt = gcnt[gr];
    if (cnt < 1.f) cnt = 1.f;
    for (int i = t; i < 3 * D; i += 64) g[i] = gsum[gr * 3 * D + i] / cnt;
    __syncthreads();

    float acc = b1[t];
#pragma unroll 8
    for (int k = 0; k < 3 * D; ++k) acc += g[k] * W1[k * D + t];
    tt[t] = acc > 0.f ? acc : 0.f;
    __syncthreads();

    if (t < D_TARGET) {
        float acc2 = b2[t];
#pragma unroll
        for (int k = 0; k < D; ++k) acc2 += tt[k] * W2[k * D_TARGET + t];
        out[gr * D_TARGET + t] = acc2;
    }
}

extern "C" void kernel_launch(void* const* d_in, const int* in_sizes, int n_in,
                              void* d_out, int out_size, void* d_ws, size_t ws_size,
                              hipStream_t stream) {
    const float* x     = (const float*)d_in[0];
    const int*   ei    = (const int*)d_in[1];   // [2][N_EDGES], int64 in ref -> int32 per harness
    const int*   src   = ei;
    const int*   dst   = ei + N_EDGES;
    const int*   batch = (const int*)d_in[2];

    const float* Wl[3] = {(const float*)d_in[3], (const float*)d_in[6], (const float*)d_in[9]};
    const float* bl[3] = {(const float*)d_in[4], (const float*)d_in[7], (const float*)d_in[10]};
    const float* Wr[3] = {(const float*)d_in[5], (const float*)d_in[8], (const float*)d_in[11]};
    const float* Wm = (const float*)d_in[12];
    const float* bm = (const float*)d_in[13];
    const float* W1 = (const float*)d_in[14];
    const float* b1 = (const float*)d_in[15];
    const float* W2 = (const float*)d_in[16];
    const float* b2 = (const float*)d_in[17];

    // workspace layout (floats)
    float* ws   = (float*)d_ws;
    float* agg  = ws;                        // N_NODES*D   = 3,200,000
    float* hA   = agg + N_NODES * D;         // 3,200,000
    float* hB   = hA + N_NODES * D;          // 3,200,000
    float* deg  = hB + N_NODES * D;          // 50,000
    float* gsum = deg + N_NODES;             // 512*192 = 98,304
    float* gcnt = gsum + N_GRAPHS * 3 * D;   // 512
    // total ≈ 9.75M floats ≈ 39 MB

    // zero deg + gsum + gcnt (contiguous)
    hipMemsetAsync(deg, 0, (N_NODES + N_GRAPHS * 3 * D + N_GRAPHS) * sizeof(float), stream);
    count_kernel<<<(N_EDGES + 255) / 256, 256, 0, stream>>>(dst, batch, deg, gcnt);

    const float* hin = x;
    float* hout = hA;
    for (int l = 0; l < 3; ++l) {
        hipMemsetAsync(agg, 0, (size_t)N_NODES * D * sizeof(float), stream);
        // one wave per edge
        long long threads = (long long)N_EDGES * 64;
        scatter_kernel<<<(int)((threads + 255) / 256), 256, 0, stream>>>(hin, src, dst, agg);
        node_kernel<4><<<(N_NODES + 3) / 4, 256, 0, stream>>>(
            hin, agg, deg, Wl[l], bl[l], Wr[l], Wm, bm, batch, hout, gsum, l * D);
        hin  = hout;
        hout = (hout == hA) ? hB : hA;
    }

    pool_mlp_kernel<<<N_GRAPHS, 64, 0, stream>>>(gsum, gcnt, W1, b1, W2, b2, (float*)d_out);
}

// Round 2
// 498.675 us; speedup vs baseline: 1.9661x; 1.9661x over previous
//
#include <hip/hip_runtime.h>

// GraphSAGE forward: CSR-gather formulation.
// 3×(SAGEConv + shared Wm/ReLU) -> concat -> global mean pool -> MLP
#define N_NODES 50000
#define N_EDGES 800000
#define D 64
#define N_GRAPHS 512
#define D_TARGET 10
#define NB_SCAN ((N_NODES + 255) / 256)   // 196

// ---- int degree histogram + float graph-count ----
__global__ void count_kernel(const int* __restrict__ dst, const int* __restrict__ batch,
                             int* __restrict__ degi, float* __restrict__ gcnt) {
    int i = blockIdx.x * blockDim.x + threadIdx.x;
    if (i < N_EDGES) atomicAdd(&degi[dst[i]], 1);
    if (i < N_NODES) atomicAdd(&gcnt[batch[i]], 1.0f);
}

// ---- scan step 1: per-256-chunk sums ----
__global__ void scan_partials(const int* __restrict__ degi, int* __restrict__ partial) {
    __shared__ int s[256];
    int t = threadIdx.x;
    int i = blockIdx.x * 256 + t;
    s[t] = (i < N_NODES) ? degi[i] : 0;
    __syncthreads();
    for (int off = 128; off > 0; off >>= 1) {
        if (t < off) s[t] += s[t + off];
        __syncthreads();
    }
    if (t == 0) partial[blockIdx.x] = s[0];
}

// ---- scan step 2: exclusive scan of the 196 partials (serial, trivial) ----
__global__ void scan_offsets(int* __restrict__ partial) {
    if (threadIdx.x == 0) {
        int run = 0;
        for (int i = 0; i < NB_SCAN; ++i) { int p = partial[i]; partial[i] = run; run += p; }
    }
}

// ---- scan step 3: per-chunk Hillis-Steele -> rowptr; also init next=rowptr ----
__global__ void scan_final(const int* __restrict__ degi, const int* __restrict__ partial,
                           int* __restrict__ rowptr, int* __restrict__ next) {
    __shared__ int s[256];
    int t = threadIdx.x;
    int i = blockIdx.x * 256 + t;
    int v = (i < N_NODES) ? degi[i] : 0;
    s[t] = v;
    __syncthreads();
    for (int off = 1; off < 256; off <<= 1) {
        int add = (t >= off) ? s[t - off] : 0;
        __syncthreads();
        s[t] += add;
        __syncthreads();
    }
    if (i < N_NODES) {
        int excl = partial[blockIdx.x] + s[t] - v;
        rowptr[i] = excl;
        next[i]   = excl;
    }
    if (i == 0) rowptr[N_NODES] = N_EDGES;
}

// ---- CSR fill: col[pos] = src for each edge, bucketed by dst ----
__global__ void fill_kernel(const int* __restrict__ src, const int* __restrict__ dst,
                            int* __restrict__ next, int* __restrict__ col) {
    int e = blockIdx.x * blockDim.x + threadIdx.x;
    if (e < N_EDGES) {
        int pos = atomicAdd(&next[dst[e]], 1);
        col[pos] = src[e];
    }
}

// ---- fused per-layer kernel:
//   gather-mean over CSR neighbors -> t = mean@Wl + bl + x@Wr
//   h' = relu(t@Wm + bm) -> h_out, pool atomicAdd into gsum
// NPB nodes/block, 64 lanes per node.
template <int NPB>
__global__ __launch_bounds__(NPB * 64) void sage_kernel(
    const float* __restrict__ h_in, const int* __restrict__ rowptr, const int* __restrict__ col,
    const float* __restrict__ Wl, const float* __restrict__ bl, const float* __restrict__ Wr,
    const float* __restrict__ Wm, const float* __restrict__ bm,
    const int* __restrict__ batch,
    float* __restrict__ h_out, float* __restrict__ gsum, int col_off) {
    __shared__ float sWl[D * D];
    __shared__ float sWr[D * D];
    __shared__ float sWm[D * D];
    __shared__ float sx[NPB][D];
    __shared__ float sm[NPB][D];
    __shared__ float st[NPB][D];

    int t = threadIdx.x;
    for (int i = t; i < D * D; i += NPB * 64) {
        sWl[i] = Wl[i];
        sWr[i] = Wr[i];
        sWm[i] = Wm[i];
    }
    int sub  = t >> 6;
    int lane = t & 63;
    int node = blockIdx.x * NPB + sub;

    float xv = 0.f, mv = 0.f;
    if (node < N_NODES) {
        xv = h_in[node * D + lane];
        int beg = rowptr[node], end = rowptr[node + 1];
        float acc = 0.f;
        for (int base = beg; base < end; base += 64) {
            int nrem = end - base;
            int c    = (lane < nrem) ? col[base + lane] : 0;
            int cnt  = nrem < 64 ? nrem : 64;
            for (int j = 0; j < cnt; ++j) {
                int s = __shfl(c, j);
                acc += h_in[s * D + lane];
            }
        }
        float dg = (float)(end - beg);
        if (dg < 1.f) dg = 1.f;
        mv = acc / dg;
    }
    sx[sub][lane] = xv;
    sm[sub][lane] = mv;
    __syncthreads();

    float acc = bl[lane];
#pragma unroll 8
    for (int k = 0; k < D; ++k)
        acc += sm[sub][k] * sWl[k * D + lane] + sx[sub][k] * sWr[k * D + lane];
    st[sub][lane] = acc;
    __syncthreads();

    float acc2 = bm[lane];
#pragma unroll 8
    for (int k = 0; k < D; ++k)
        acc2 += st[sub][k] * sWm[k * D + lane];
    float hv = acc2 > 0.f ? acc2 : 0.f;

    if (node < N_NODES) {
        h_out[node * D + lane] = hv;
        atomicAdd(&gsum[batch[node] * (3 * D) + col_off + lane], hv);
    }
}

// ---- pooled MLP: g = gsum/cnt; t = relu(g@W1+b1); out = t@W2+b2 ----
__global__ void pool_mlp_kernel(const float* __restrict__ gsum, const float* __restrict__ gcnt,
                                const float* __restrict__ W1, const float* __restrict__ b1,
                                const float* __restrict__ W2, const float* __restrict__ b2,
                                float* __restrict__ out) {
    __shared__ float g[3 * D];
    __shared__ float tt[D];
    int gr = blockIdx.x;
    int t  = threadIdx.x;  // 64 threads
    float cnt = gcnt[gr];
    if (cnt < 1.f) cnt = 1.f;
    for (int i = t; i < 3 * D; i += 64) g[i] = gsum[gr * 3 * D + i] / cnt;
    __syncthreads();

    float acc = b1[t];
#pragma unroll 8
    for (int k = 0; k < 3 * D; ++k) acc += g[k] * W1[k * D + t];
    tt[t] = acc > 0.f ? acc : 0.f;
    __syncthreads();

    if (t < D_TARGET) {
        float acc2 = b2[t];
#pragma unroll
        for (int k = 0; k < D; ++k) acc2 += tt[k] * W2[k * D_TARGET + t];
        out[gr * D_TARGET + t] = acc2;
    }
}

extern "C" void kernel_launch(void* const* d_in, const int* in_sizes, int n_in,
                              void* d_out, int out_size, void* d_ws, size_t ws_size,
                              hipStream_t stream) {
    const float* x     = (const float*)d_in[0];
    const int*   ei    = (const int*)d_in[1];
    const int*   src   = ei;
    const int*   dst   = ei + N_EDGES;
    const int*   batch = (const int*)d_in[2];

    const float* Wl[3] = {(const float*)d_in[3], (const float*)d_in[6], (const float*)d_in[9]};
    const float* bl[3] = {(const float*)d_in[4], (const float*)d_in[7], (const float*)d_in[10]};
    const float* Wr[3] = {(const float*)d_in[5], (const float*)d_in[8], (const float*)d_in[11]};
    const float* Wm = (const float*)d_in[12];
    const float* bm = (const float*)d_in[13];
    const float* W1 = (const float*)d_in[14];
    const float* b1 = (const float*)d_in[15];
    const float* W2 = (const float*)d_in[16];
    const float* b2 = (const float*)d_in[17];

    // workspace layout
    int*   degi    = (int*)d_ws;                       // 50000
    float* gsum    = (float*)(degi + N_NODES);         // 512*192 = 98304
    float* gcnt    = gsum + N_GRAPHS * 3 * D;          // 512
    int*   partial = (int*)(gcnt + N_GRAPHS);          // 256 (196 used)
    int*   rowptr  = partial + 256;                    // 50001
    int*   next    = rowptr + N_NODES + 1;             // 50000
    int*   col     = next + N_NODES;                   // 800000
    float* hA      = (float*)(col + N_EDGES);          // 3,200,000
    float* hB      = hA + (size_t)N_NODES * D;         // 3,200,000
    // total ≈ 30 MB

    // zero degi + gsum + gcnt (contiguous range)
    hipMemsetAsync(degi, 0, (N_NODES + N_GRAPHS * 3 * D + N_GRAPHS) * sizeof(float), stream);

    count_kernel<<<(N_EDGES + 255) / 256, 256, 0, stream>>>(dst, batch, degi, gcnt);
    scan_partials<<<NB_SCAN, 256, 0, stream>>>(degi, partial);
    scan_offsets<<<1, 64, 0, stream>>>(partial);
    scan_final<<<NB_SCAN, 256, 0, stream>>>(degi, partial, rowptr, next);
    fill_kernel<<<(N_EDGES + 255) / 256, 256, 0, stream>>>(src, dst, next, col);

    const float* hin = x;
    float* hout = hA;
    for (int l = 0; l < 3; ++l) {
        sage_kernel<16><<<(N_NODES + 15) / 16, 16 * 64, 0, stream>>>(
            hin, rowptr, col, Wl[l], bl[l], Wr[l], Wm, bm, batch, hout, gsum, l * D);
        hin  = hout;
        hout = (hout == hA) ? hB : hA;
    }

    pool_mlp_kernel<<<N_GRAPHS, 64, 0, stream>>>(gsum, gcnt, W1, b1, W2, b2, (float*)d_out);
}

// Round 3
// 431.839 us; speedup vs baseline: 2.2704x; 1.1548x over previous
//
#include <hip/hip_runtime.h>

// GraphSAGE forward: CSR-gather, subgroup-parallel float4 gather,
// transposed-padded LDS weights for b128 column reads.
#define N_NODES 50000
#define N_EDGES 800000
#define D 64
#define N_GRAPHS 512
#define D_TARGET 10
#define NB_SCAN ((N_NODES + 255) / 256)   // 196
#define WPAD 68                            // 64 + 4 pad: stride 17 float4 -> conflict-free b128

// ---- int degree histogram + float graph-count ----
__global__ void count_kernel(const int* __restrict__ dst, const int* __restrict__ batch,
                             int* __restrict__ degi, float* __restrict__ gcnt) {
    int i = blockIdx.x * blockDim.x + threadIdx.x;
    if (i < N_EDGES) atomicAdd(&degi[dst[i]], 1);
    if (i < N_NODES) atomicAdd(&gcnt[batch[i]], 1.0f);
}

// ---- scan step 1: per-256-chunk sums ----
__global__ void scan_partials(const int* __restrict__ degi, int* __restrict__ partial) {
    __shared__ int s[256];
    int t = threadIdx.x;
    int i = blockIdx.x * 256 + t;
    s[t] = (i < N_NODES) ? degi[i] : 0;
    __syncthreads();
    for (int off = 128; off > 0; off >>= 1) {
        if (t < off) s[t] += s[t + off];
        __syncthreads();
    }
    if (t == 0) partial[blockIdx.x] = s[0];
}

// ---- scan step 2: exclusive scan of the partials ----
__global__ void scan_offsets(int* __restrict__ partial) {
    if (threadIdx.x == 0) {
        int run = 0;
        for (int i = 0; i < NB_SCAN; ++i) { int p = partial[i]; partial[i] = run; run += p; }
    }
}

// ---- scan step 3: per-chunk inclusive scan -> exclusive rowptr; next=rowptr ----
__global__ void scan_final(const int* __restrict__ degi, const int* __restrict__ partial,
                           int* __restrict__ rowptr, int* __restrict__ next) {
    __shared__ int s[256];
    int t = threadIdx.x;
    int i = blockIdx.x * 256 + t;
    int v = (i < N_NODES) ? degi[i] : 0;
    s[t] = v;
    __syncthreads();
    for (int off = 1; off < 256; off <<= 1) {
        int add = (t >= off) ? s[t - off] : 0;
        __syncthreads();
        s[t] += add;
        __syncthreads();
    }
    if (i < N_NODES) {
        int excl = partial[blockIdx.x] + s[t] - v;
        rowptr[i] = excl;
        next[i]   = excl;
    }
    if (i == 0) rowptr[N_NODES] = N_EDGES;
}

// ---- CSR fill: col[pos] = src for each edge, bucketed by dst ----
__global__ void fill_kernel(const int* __restrict__ src, const int* __restrict__ dst,
                            int* __restrict__ next, int* __restrict__ col) {
    int e = blockIdx.x * blockDim.x + threadIdx.x;
    if (e < N_EDGES) {
        int pos = atomicAdd(&next[dst[e]], 1);
        col[pos] = src[e];
    }
}

// ---- fused per-layer kernel ----
// Wave per node. Gather: 4 subgroups x 16 lanes, float4 per lane.
// Matmuls: lane = output feature, b128 column reads from transposed padded weights.
template <int NPB>
__global__ __launch_bounds__(NPB * 64) void sage_kernel(
    const float* __restrict__ h_in, const int* __restrict__ rowptr, const int* __restrict__ col,
    const float* __restrict__ Wl, const float* __restrict__ bl, const float* __restrict__ Wr,
    const float* __restrict__ Wm, const float* __restrict__ bm,
    const int* __restrict__ batch,
    float* __restrict__ h_out, float* __restrict__ gsum, int col_off) {
    __shared__ float sWlT[D * WPAD];
    __shared__ float sWrT[D * WPAD];
    __shared__ float sWmT[D * WPAD];
    __shared__ float sx[NPB][D];
    __shared__ float sm[NPB][D];

    int t = threadIdx.x;
    // stage transposed weights: sWT[o][k] = W[k*D + o]
    for (int i = t; i < D * D; i += NPB * 64) {
        int k = i >> 6, o = i & 63;
        sWlT[o * WPAD + k] = Wl[i];
        sWrT[o * WPAD + k] = Wr[i];
        sWmT[o * WPAD + k] = Wm[i];
    }
    __syncthreads();

    int sub  = t >> 6;
    int lane = t & 63;
    int f    = lane & 15;   // float4 index within feature row
    int g    = lane >> 4;   // neighbor subgroup 0..3
    int node = blockIdx.x * NPB + sub;

    const float4* h4 = (const float4*)h_in;
    float4* sm4 = (float4*)sm[sub];
    float4* sx4 = (float4*)sx[sub];

    if (node < N_NODES) {
        int beg = rowptr[node], end = rowptr[node + 1];
        float4 acc4 = make_float4(0.f, 0.f, 0.f, 0.f);
        for (int base = beg + g; base < end; base += 4) {
            int s = col[base];
            float4 v = h4[s * 16 + f];
            acc4.x += v.x; acc4.y += v.y; acc4.z += v.z; acc4.w += v.w;
        }
        // reduce across the 4 subgroups (lanes ^16, ^32)
        acc4.x += __shfl_xor(acc4.x, 16); acc4.y += __shfl_xor(acc4.y, 16);
        acc4.z += __shfl_xor(acc4.z, 16); acc4.w += __shfl_xor(acc4.w, 16);
        acc4.x += __shfl_xor(acc4.x, 32); acc4.y += __shfl_xor(acc4.y, 32);
        acc4.z += __shfl_xor(acc4.z, 32); acc4.w += __shfl_xor(acc4.w, 32);
        float dg = (float)(end - beg);
        if (dg < 1.f) dg = 1.f;
        float inv = 1.f / dg;
        if (g == 0) {
            sm4[f] = make_float4(acc4.x * inv, acc4.y * inv, acc4.z * inv, acc4.w * inv);
            sx4[f] = h4[node * 16 + f];
        }
    }
    // wave-local LDS: per-wave in-order, no block barrier needed

    const float4* wl4 = (const float4*)sWlT;
    const float4* wr4 = (const float4*)sWrT;
    const float4* wm4 = (const float4*)sWmT;
    int o17 = lane * (WPAD / 4);

    float acc = bl[lane];
#pragma unroll
    for (int q = 0; q < 16; ++q) {
        float4 m = sm4[q];
        float4 x = sx4[q];
        float4 a = wl4[o17 + q];
        float4 b = wr4[o17 + q];
        acc += m.x * a.x + m.y * a.y + m.z * a.z + m.w * a.w;
        acc += x.x * b.x + x.y * b.y + x.z * b.z + x.w * b.w;
    }
    sm[sub][lane] = acc;  // reuse sm for intermediate t (same wave reads below)

    float acc2 = bm[lane];
#pragma unroll
    for (int q = 0; q < 16; ++q) {
        float4 tt = sm4[q];
        float4 w  = wm4[o17 + q];
        acc2 += tt.x * w.x + tt.y * w.y + tt.z * w.z + tt.w * w.w;
    }
    float hv = acc2 > 0.f ? acc2 : 0.f;

    if (node < N_NODES) {
        h_out[node * D + lane] = hv;
        atomicAdd(&gsum[batch[node] * (3 * D) + col_off + lane], hv);
    }
}

// ---- pooled MLP: g = gsum/cnt; t = relu(g@W1+b1); out = t@W2+b2 ----
__global__ void pool_mlp_kernel(const float* __restrict__ gsum, const float* __restrict__ gcnt,
                                const float* __restrict__ W1, const float* __restrict__ b1,
                                const float* __restrict__ W2, const float* __restrict__ b2,
                                float* __restrict__ out) {
    __shared__ float g[3 * D];
    __shared__ float tt[D];
    int gr = blockIdx.x;
    int t  = threadIdx.x;  // 64 threads
    float cnt = gcnt[gr];
    if (cnt < 1.f) cnt = 1.f;
    for (int i = t; i < 3 * D; i += 64) g[i] = gsum[gr * 3 * D + i] / cnt;
    __syncthreads();

    float acc = b1[t];
#pragma unroll 8
    for (int k = 0; k < 3 * D; ++k) acc += g[k] * W1[k * D + t];
    tt[t] = acc > 0.f ? acc : 0.f;
    __syncthreads();

    if (t < D_TARGET) {
        float acc2 = b2[t];
#pragma unroll
        for (int k = 0; k < D; ++k) acc2 += tt[k] * W2[k * D_TARGET + t];
        out[gr * D_TARGET + t] = acc2;
    }
}

extern "C" void kernel_launch(void* const* d_in, const int* in_sizes, int n_in,
                              void* d_out, int out_size, void* d_ws, size_t ws_size,
                              hipStream_t stream) {
    const float* x     = (const float*)d_in[0];
    const int*   ei    = (const int*)d_in[1];
    const int*   src   = ei;
    const int*   dst   = ei + N_EDGES;
    const int*   batch = (const int*)d_in[2];

    const float* Wl[3] = {(const float*)d_in[3], (const float*)d_in[6], (const float*)d_in[9]};
    const float* bl[3] = {(const float*)d_in[4], (const float*)d_in[7], (const float*)d_in[10]};
    const float* Wr[3] = {(const float*)d_in[5], (const float*)d_in[8], (const float*)d_in[11]};
    const float* Wm = (const float*)d_in[12];
    const float* bm = (const float*)d_in[13];
    const float* W1 = (const float*)d_in[14];
    const float* b1 = (const float*)d_in[15];
    const float* W2 = (const float*)d_in[16];
    const float* b2 = (const float*)d_in[17];

    // workspace layout
    int*   degi    = (int*)d_ws;                       // 50000
    float* gsum    = (float*)(degi + N_NODES);         // 98304
    float* gcnt    = gsum + N_GRAPHS * 3 * D;          // 512
    int*   partial = (int*)(gcnt + N_GRAPHS);          // 256
    int*   rowptr  = partial + 256;                    // 50001
    int*   next    = rowptr + N_NODES + 1;             // 50000
    int*   col     = next + N_NODES;                   // 800000
    float* hA      = (float*)(col + N_EDGES);          // 3,200,000
    float* hB      = hA + (size_t)N_NODES * D;         // 3,200,000

    // zero degi + gsum + gcnt (contiguous)
    hipMemsetAsync(degi, 0, (N_NODES + N_GRAPHS * 3 * D + N_GRAPHS) * sizeof(float), stream);

    count_kernel<<<(N_EDGES + 255) / 256, 256, 0, stream>>>(dst, batch, degi, gcnt);
    scan_partials<<<NB_SCAN, 256, 0, stream>>>(degi, partial);
    scan_offsets<<<1, 64, 0, stream>>>(partial);
    scan_final<<<NB_SCAN, 256, 0, stream>>>(degi, partial, rowptr, next);
    fill_kernel<<<(N_EDGES + 255) / 256, 256, 0, stream>>>(src, dst, next, col);

    const float* hin = x;
    float* hout = hA;
    for (int l = 0; l < 3; ++l) {
        sage_kernel<16><<<(N_NODES + 15) / 16, 16 * 64, 0, stream>>>(
            hin, rowptr, col, Wl[l], bl[l], Wr[l], Wm, bm, batch, hout, gsum, l * D);
        hin  = hout;
        hout = (hout == hA) ? hB : hA;
    }

    pool_mlp_kernel<<<N_GRAPHS, 64, 0, stream>>>(gsum, gcnt, W1, b1, W2, b2, (float*)d_out);
}